// Round 1
// baseline (318.824 us; speedup 1.0000x reference)
//
#include <hip/hip_runtime.h>

typedef __attribute__((ext_vector_type(8))) short bf16x8;
typedef __attribute__((ext_vector_type(4))) float f32x4;

#define LOG2E 1.4426950408889634f

__device__ __forceinline__ unsigned short f2bf(float f) {
  unsigned int x = __builtin_bit_cast(unsigned int, f);
  x += 0x7fffu + ((x >> 16) & 1u);   // RNE
  return (unsigned short)(x >> 16);
}
__device__ __forceinline__ float bf2f(unsigned short u) {
  unsigned int x = ((unsigned int)u) << 16;
  return __builtin_bit_cast(float, x);
}

__device__ __forceinline__ void gload16(const void* g, void* l) {
  __builtin_amdgcn_global_load_lds((const __attribute__((address_space(1))) void*)g,
                                   (__attribute__((address_space(3))) void*)l, 16, 0, 0);
}

// ---------------------------------------------------------------- cast + pack
// x -> xb (bf16); wq*1/sqrt(128), wk, wv -> wqkv packed; wo -> wob
__global__ __launch_bounds__(256)
void cast_pack(const float* __restrict__ x, const float* __restrict__ wq,
               const float* __restrict__ wk, const float* __restrict__ wv,
               const float* __restrict__ wo,
               unsigned short* __restrict__ xb, unsigned short* __restrict__ wqkv,
               unsigned short* __restrict__ wob) {
  const int NX = 8388608, DD = 4194304;
  const int i = (blockIdx.x * 256 + threadIdx.x) * 4;
  const float* src; unsigned short* dst; float scale = 1.0f;
  if (i < NX)               { src = x + i;                    dst = xb + i; }
  else if (i < NX + DD)     { int o = i - NX;      src = wq + o; dst = wqkv + o; scale = 0.088388347648318447f; }
  else if (i < NX + 2*DD)   { int o = i - NX - DD;   src = wk + o; dst = wqkv + DD + o; }
  else if (i < NX + 3*DD)   { int o = i - NX - 2*DD; src = wv + o; dst = wqkv + 2*DD + o; }
  else                      { int o = i - NX - 3*DD; src = wo + o; dst = wob + o; }
  const float4 v = *(const float4*)src;
  ushort4 u;
  u.x = f2bf(v.x * scale); u.y = f2bf(v.y * scale);
  u.z = f2bf(v.z * scale); u.w = f2bf(v.w * scale);
  *(ushort4*)dst = u;
}

// ---------------------------------------------------------------- GEMM C = A @ B^T
// A: [M][K] bf16 row-major, Bw: [N][K] bf16 row-major. 128x128 tile, BK=32,
// 4 waves, m97 structure (global_load_lds w=16 + ds_read_b128 + 16x16x32 MFMA).
// MODE 0: QKV epilogue (bf16 -> Qb / Kb / Vt-transposed). MODE 1: f32 -> Of.
template<int MODE>
__global__ __launch_bounds__(256)
void gemm_bt(const unsigned short* __restrict__ A, const unsigned short* __restrict__ Bw,
             float* __restrict__ Of, unsigned short* __restrict__ Qb,
             unsigned short* __restrict__ Kb, unsigned short* __restrict__ Vt, int K) {
  __shared__ unsigned short As[128 * 32];
  __shared__ unsigned short Bs[128 * 32];
  const int tid = threadIdx.x;
  const int l = tid & 63, w = tid >> 6;
  const int bm = blockIdx.y, bn = blockIdx.x;
  const int wr = w >> 1, wc = w & 1;
  const int lq = l & 15, g = l >> 4;
  const unsigned short* Ab = A + (long long)bm * 128 * K;
  const unsigned short* Bb = Bw + (long long)bn * 128 * K;
  const int srow = l >> 2, skk = (l & 3) * 8;
  f32x4 acc[4][4] = {};
  for (int k0 = 0; k0 < K; k0 += 32) {
#pragma unroll
    for (int c = 0; c < 2; ++c) {
      const int r0 = (w * 2 + c) * 16;
      gload16(Ab + (long long)(r0 + srow) * K + k0 + skk, &As[r0 * 32]);
      gload16(Bb + (long long)(r0 + srow) * K + k0 + skk, &Bs[r0 * 32]);
    }
    __syncthreads();
    bf16x8 af[4], bq[4];
#pragma unroll
    for (int mi = 0; mi < 4; ++mi)
      af[mi] = *(const bf16x8*)&As[(wr * 64 + mi * 16 + lq) * 32 + g * 8];
#pragma unroll
    for (int ni = 0; ni < 4; ++ni)
      bq[ni] = *(const bf16x8*)&Bs[(wc * 64 + ni * 16 + lq) * 32 + g * 8];
#pragma unroll
    for (int mi = 0; mi < 4; ++mi)
#pragma unroll
      for (int ni = 0; ni < 4; ++ni)
        acc[mi][ni] = __builtin_amdgcn_mfma_f32_16x16x32_bf16(af[mi], bq[ni], acc[mi][ni], 0, 0, 0);
    __syncthreads();
  }
  // D layout: col = lq, row = g*4 + r  (m89-verified)
  if (MODE == 0) {
    const int colb = bn * 128;
    if (colb < 4096) {
      unsigned short* dst = (colb < 2048) ? Qb : Kb;
      const int cb = colb & 2047;
#pragma unroll
      for (int mi = 0; mi < 4; ++mi) {
        const int row = bm * 128 + wr * 64 + mi * 16 + g * 4;
#pragma unroll
        for (int ni = 0; ni < 4; ++ni) {
          const int col = cb + wc * 64 + ni * 16 + lq;
#pragma unroll
          for (int r = 0; r < 4; ++r)
            dst[(long long)(row + r) * 2048 + col] = f2bf(acc[mi][ni][r]);
        }
      }
    } else {
      // V: write transposed -> Vt[((b*16+h)*128 + d)][s], 4 consecutive s per lane
#pragma unroll
      for (int mi = 0; mi < 4; ++mi) {
        const int row = bm * 128 + wr * 64 + mi * 16 + g * 4;   // b*2048 + s
        const int b = row >> 11, s = row & 2047;
#pragma unroll
        for (int ni = 0; ni < 4; ++ni) {
          const int c = colb - 4096 + wc * 64 + ni * 16 + lq;   // h*128 + d
          const int h = c >> 7, d = c & 127;
          ushort4 o4;
          o4.x = f2bf(acc[mi][ni][0]); o4.y = f2bf(acc[mi][ni][1]);
          o4.z = f2bf(acc[mi][ni][2]); o4.w = f2bf(acc[mi][ni][3]);
          *(ushort4*)&Vt[((long long)((b * 16 + h) * 128 + d)) * 2048 + s] = o4;
        }
      }
    }
  } else {
#pragma unroll
    for (int mi = 0; mi < 4; ++mi) {
      const int row = bm * 128 + wr * 64 + mi * 16 + g * 4;
#pragma unroll
      for (int ni = 0; ni < 4; ++ni) {
        const int col = bn * 128 + wc * 64 + ni * 16 + lq;
#pragma unroll
        for (int r = 0; r < 4; ++r)
          Of[(long long)(row + r) * 2048 + col] = acc[mi][ni][r];
      }
    }
  }
}

// ---------------------------------------------------------------- RoPE (in place on Q,K)
__global__ __launch_bounds__(256)
void rope_k(unsigned short* __restrict__ Qb, unsigned short* __restrict__ Kb,
            const float* __restrict__ fc, const float* __restrict__ fs) {
  const int t = blockIdx.x * 256 + threadIdx.x;       // 0 .. 2*2^20-1
  unsigned short* base = (t & 1048576) ? Kb : Qb;
  const int tt = t & 1048575;
  const int bs = tt >> 8;       // b*2048 + s
  const int qi = tt & 255;      // 8-elem chunk within row of 2048
  const int s = bs & 2047;
  const int c0 = (qi & 15) * 4; // pair index within head
  unsigned short* p = base + (long long)bs * 2048 + qi * 8;
  uint4 v = *(uint4*)p;
  unsigned short* ep = (unsigned short*)&v;
  const float4 cv = *(const float4*)&fc[s * 64 + c0];
  const float4 snv = *(const float4*)&fs[s * 64 + c0];
  const float cc[4] = {cv.x, cv.y, cv.z, cv.w};
  const float ss[4] = {snv.x, snv.y, snv.z, snv.w};
#pragma unroll
  for (int j = 0; j < 4; ++j) {
    const float r = bf2f(ep[2 * j]), im = bf2f(ep[2 * j + 1]);
    const float orr = r * cc[j] - im * ss[j];
    const float oi  = r * ss[j] + im * cc[j];
    ep[2 * j]     = f2bf(orr);
    ep[2 * j + 1] = f2bf(oi);
  }
  *(uint4*)p = v;
}

// ---------------------------------------------------------------- sliding-window attention
// grid (qb=32, bh=32), 256 thr = 4 waves, wave handles 16 q rows.
// Swapped QK^T: S^T = K@Q^T so D col = q (lane-uniform per lq). P round-trips
// through swizzled per-wave LDS to become B-frag of out^T = V^T @ P^T.
__global__ __launch_bounds__(256)
void attn_k(const unsigned short* __restrict__ Qb, const unsigned short* __restrict__ Kb,
            const unsigned short* __restrict__ Vt, unsigned short* __restrict__ Ob) {
  __shared__ unsigned short plds[4096];   // 4 waves x [16 q][64 key] bf16
  const int tid = threadIdx.x;
  const int l = tid & 63, w = tid >> 6;
  const int lq = l & 15, g = l >> 4;
  const int qb = blockIdx.x, bh = blockIdx.y;
  const int b = bh >> 4, h = bh & 15;
  const int q_abs = qb * 64 + w * 16 + lq;
  const unsigned short* Qrow = Qb + ((long long)(b * 2048 + q_abs)) * 2048 + h * 128;
  bf16x8 qf[4];
#pragma unroll
  for (int ks = 0; ks < 4; ++ks)
    qf[ks] = *(const bf16x8*)&Qrow[ks * 32 + g * 8];
  f32x4 o[8] = {};
  float m = -1e30f, lsum = 0.0f;
  char* pb = (char*)(plds + w * 1024);
  const unsigned short* Kbase = Kb + ((long long)(b * 2048)) * 2048 + h * 128;
  const unsigned short* Vbase = Vt + ((long long)bh) * 128 * 2048;
  const int kb_lo = (qb >= 4) ? qb - 4 : 0;
  for (int kb = kb_lo; kb <= qb; ++kb) {
    const int key0 = kb * 64;
    f32x4 sc[4] = {};
#pragma unroll
    for (int mt = 0; mt < 4; ++mt) {
      const unsigned short* Krow = Kbase + (long long)(key0 + mt * 16 + lq) * 2048;
#pragma unroll
      for (int ks = 0; ks < 4; ++ks) {
        const bf16x8 kf = *(const bf16x8*)&Krow[ks * 32 + g * 8];
        sc[mt] = __builtin_amdgcn_mfma_f32_16x16x32_bf16(kf, qf[ks], sc[mt], 0, 0, 0);
      }
    }
    // mask + online softmax (per lane: q = lq; keys = key0 + mt*16 + g*4 + r)
    float sv[16];
    float bmax = -1e30f;
#pragma unroll
    for (int mt = 0; mt < 4; ++mt)
#pragma unroll
      for (int r = 0; r < 4; ++r) {
        const int key = key0 + mt * 16 + g * 4 + r;
        float xv = sc[mt][r];
        const bool valid = (key <= q_abs) && (key + 256 > q_abs);
        xv = valid ? xv : -1e30f;
        sv[mt * 4 + r] = xv;
        bmax = fmaxf(bmax, xv);
      }
    bmax = fmaxf(bmax, __shfl_xor(bmax, 16));
    bmax = fmaxf(bmax, __shfl_xor(bmax, 32));
    const float mnew = fmaxf(m, bmax);
    const float rf = __builtin_exp2f((m - mnew) * LOG2E);
    float psum = 0.0f;
#pragma unroll
    for (int i = 0; i < 16; ++i) {
      const float p = __builtin_exp2f((sv[i] - mnew) * LOG2E);
      sv[i] = p;
      psum += p;
    }
    psum += __shfl_xor(psum, 16);
    psum += __shfl_xor(psum, 32);
    lsum = lsum * rf + psum;
    m = mnew;
#pragma unroll
    for (int dt = 0; dt < 8; ++dt) o[dt] *= rf;
    // P -> LDS [q][key], XOR-swizzled
#pragma unroll
    for (int mt = 0; mt < 4; ++mt) {
      const unsigned int lo = (unsigned int)f2bf(sv[mt * 4 + 0]) | ((unsigned int)f2bf(sv[mt * 4 + 1]) << 16);
      const unsigned int hi = (unsigned int)f2bf(sv[mt * 4 + 2]) | ((unsigned int)f2bf(sv[mt * 4 + 3]) << 16);
      int byte = lq * 128 + (mt * 16 + g * 4) * 2;
      byte ^= (lq & 7) << 4;
      *(uint2*)(pb + byte) = make_uint2(lo, hi);
    }
    __syncthreads();
    bf16x8 pf[2];
#pragma unroll
    for (int k2 = 0; k2 < 2; ++k2) {
      int byte = lq * 128 + k2 * 64 + g * 16;
      byte ^= (lq & 7) << 4;
      pf[k2] = *(const bf16x8*)(pb + byte);
    }
#pragma unroll
    for (int dt = 0; dt < 8; ++dt) {
      const unsigned short* Vrow = Vbase + (long long)(dt * 16 + lq) * 2048 + key0;
#pragma unroll
      for (int k2 = 0; k2 < 2; ++k2) {
        const bf16x8 vf = *(const bf16x8*)&Vrow[k2 * 32 + g * 8];
        o[dt] = __builtin_amdgcn_mfma_f32_16x16x32_bf16(vf, pf[k2], o[dt], 0, 0, 0);
      }
    }
    __syncthreads();
  }
  const float inv = 1.0f / lsum;
  unsigned short* Or = Ob + ((long long)(b * 2048 + q_abs)) * 2048 + h * 128;
#pragma unroll
  for (int dt = 0; dt < 8; ++dt) {
    ushort4 o4;
    o4.x = f2bf(o[dt][0] * inv);
    o4.y = f2bf(o[dt][1] * inv);
    o4.z = f2bf(o[dt][2] * inv);
    o4.w = f2bf(o[dt][3] * inv);
    *(ushort4*)&Or[dt * 16 + g * 4] = o4;
  }
}

// ----------------------------------------------------------------
extern "C" void kernel_launch(void* const* d_in, const int* in_sizes, int n_in,
                              void* d_out, int out_size, void* d_ws, size_t ws_size,
                              hipStream_t stream) {
  const float* x  = (const float*)d_in[0];
  const float* fc = (const float*)d_in[1];
  const float* fs = (const float*)d_in[2];
  const float* wq = (const float*)d_in[3];
  const float* wk = (const float*)d_in[4];
  const float* wv = (const float*)d_in[5];
  const float* wo = (const float*)d_in[6];

  unsigned short* ws   = (unsigned short*)d_ws;
  unsigned short* xb   = ws;                       //  8388608
  unsigned short* wqkv = xb + 8388608;             // 12582912
  unsigned short* wob  = wqkv + 12582912;          //  4194304
  unsigned short* Qb   = wob + 4194304;            //  8388608
  unsigned short* Kb   = Qb + 8388608;             //  8388608
  unsigned short* Vt   = Kb + 8388608;             //  8388608  [b,h,d,s]
  unsigned short* Ob   = Vt + 8388608;             //  8388608

  cast_pack<<<24576, 256, 0, stream>>>(x, wq, wk, wv, wo, xb, wqkv, wob);
  gemm_bt<0><<<dim3(48, 32), 256, 0, stream>>>(xb, wqkv, nullptr, Qb, Kb, Vt, 2048);
  rope_k<<<8192, 256, 0, stream>>>(Qb, Kb, fc, fs);
  attn_k<<<dim3(32, 32), 256, 0, stream>>>(Qb, Kb, Vt, Ob);
  gemm_bt<1><<<dim3(16, 32), 256, 0, stream>>>(Ob, wob, (float*)d_out, nullptr, nullptr, nullptr, 2048);
}